// Round 4
// baseline (156.915 us; speedup 1.0000x reference)
//
#include <hip/hip_runtime.h>

#define BATCH 2
#define NCAM 6
#define CIN 256
#define COUT 80
#define HFEAT 32
#define WFEAT 88
#define HWF (HFEAT * WFEAT)   // 2816
#define NXV 200
#define NYV 200
#define NZV 4
#define NPIX (NXV * NYV)      // 40000
#define BN_EPS 1e-5f
#define CSPLIT 2              // channel halves in k_bev
#define CHALF (COUT / CSPLIT) // 40

// ws layout: featW (B*NCAM*HWF*COUT floats = 10,813,440 B) at offset 0.
#define WS_NEED ((size_t)BATCH * NCAM * HWF * COUT * 4)

// ---------------------------------------------------------------------------
// Combined projection matrix per (b, cam):
//   p_img = (iam_r @ l2i)[:3,:] @ [[R_l^T, -R_l^T t_l],[0,0,0,1]] @ [x,y,z,1]
// plus post-offsets u += iam[0,3], v += iam[1,3].
// Stored as 16 floats: m[0..11] = 3x4 row-major, m[12]=uoff, m[13]=voff.
// With identity iam/lam (the test inputs) this folds bit-exactly to l2i.
// ---------------------------------------------------------------------------
__device__ __forceinline__ void compute_cam_mat(int b, int cam,
                                                const float* __restrict__ l2i,
                                                const float* __restrict__ iam,
                                                const float* __restrict__ lam,
                                                float* __restrict__ O /*16*/) {
    const float* L = lam + b * 16;
    const float* A = iam + (b * NCAM + cam) * 16;
    const float* P = l2i + (b * NCAM + cam) * 16;
    // T_l = [R^T | -R^T t]   (lidar_aug inverse)
    float Tl[3][4];
    #pragma unroll
    for (int i = 0; i < 3; i++) {
        #pragma unroll
        for (int j = 0; j < 3; j++) Tl[i][j] = L[j * 4 + i];
        Tl[i][3] = -(L[0 * 4 + i] * L[0 * 4 + 3] +
                     L[1 * 4 + i] * L[1 * 4 + 3] +
                     L[2 * 4 + i] * L[2 * 4 + 3]);
    }
    // Pm = rows 0..2 of iam_r @ l2i  (iam_r[i][3]=0 for i<3 -> k sums 0..2)
    float Pm[3][4];
    #pragma unroll
    for (int i = 0; i < 3; i++)
        #pragma unroll
        for (int j = 0; j < 4; j++) {
            float s = 0.f;
            #pragma unroll
            for (int k = 0; k < 3; k++) s += A[i * 4 + k] * P[k * 4 + j];
            Pm[i][j] = s;
        }
    // Mc = Pm @ [[Tl],[0,0,0,1]]
    #pragma unroll
    for (int i = 0; i < 3; i++) {
        #pragma unroll
        for (int j = 0; j < 4; j++) {
            float s = (j == 3) ? Pm[i][3] : 0.f;
            #pragma unroll
            for (int k = 0; k < 3; k++) s += Pm[i][k] * Tl[k][j];
            O[i * 4 + j] = s;
        }
    }
    O[12] = A[0 * 4 + 3];
    O[13] = A[1 * 4 + 3];
    O[14] = 0.f;
    O[15] = 0.f;
}

// ---------------------------------------------------------------------------
// featW[bc][hw][o] = sum_c W[o][c] * feat[bc][c][hw]
// grid (11, 12, 4), block 256. Lanes = hw (256B coalesced loads); W reads
// wave-uniform -> scalar. 2112 waves, FMA-bound floor ~9us; o-group feat
// re-reads are L3-absorbed (feat = 34.6MB < 256MB L3).
// ---------------------------------------------------------------------------
__global__ __launch_bounds__(256) void k_featw(const float* __restrict__ feat,
                                               const float* __restrict__ W,
                                               float* __restrict__ featW) {
    const int hw = blockIdx.x * 256 + threadIdx.x;   // 0..2815
    const int bc = blockIdx.y;                        // 0..11
    const int og = blockIdx.z;                        // 0..3 (20 outputs each)
    const float* f = feat + (size_t)bc * CIN * HWF + hw;
    const float* w = W + og * 20 * CIN;
    float acc[20];
    #pragma unroll
    for (int j = 0; j < 20; j++) acc[j] = 0.f;
    #pragma unroll 4
    for (int c = 0; c < CIN; c++) {
        float v = f[(size_t)c * HWF];
        #pragma unroll
        for (int j = 0; j < 20; j++) acc[j] = fmaf(v, w[j * CIN + c], acc[j]);
    }
    float* dst = featW + ((size_t)bc * HWF + hw) * COUT + og * 20;
    #pragma unroll
    for (int j = 0; j < 5; j++) {
        *reinterpret_cast<float4*>(dst + j * 4) =
            make_float4(acc[j * 4], acc[j * 4 + 1], acc[j * 4 + 2], acc[j * 4 + 3]);
    }
}

// ---------------------------------------------------------------------------
// Projection of one voxel point -> (cam*HWF + v*WFEAT + u) or -1.
// Matches reference: round-half-even (rintf == jnp.round), strict Z>0,
// bounds checked in float space BEFORE the int cast (matches XLA's
// saturating cast semantics), LAST valid camera wins (reference's
// where-chain overwrites ascending j -> iterate 5..0, take first hit).
// ---------------------------------------------------------------------------
__device__ __forceinline__ int project_point(const float* __restrict__ M /*6*16*/,
                                             float x, float y, float z) {
    for (int cam = NCAM - 1; cam >= 0; --cam) {
        const float* m = M + cam * 16;
        float Z = m[8] * x + m[9] * y + m[10] * z + m[11];
        if (Z > 0.f) {
            float u = (m[0] * x + m[1] * y + m[2] * z + m[3]) / Z + m[12];
            float v = (m[4] * x + m[5] * y + m[6] * z + m[7]) / Z + m[13];
            float uf = rintf(u * 0.125f);   // stride = 8, exact pow2 scale
            float vf = rintf(v * 0.125f);
            if (uf >= 0.f && uf < (float)WFEAT && vf >= 0.f && vf < (float)HFEAT) {
                return cam * HWF + (int)vf * WFEAT + (int)uf;
            }
        }
    }
    return -1;
}

// ---------------------------------------------------------------------------
// BN scale / folded-bias precompute into LDS (per block).
//   scale[o] = gamma[o]/sqrt(var[o]+eps); bias[o] = (cb[o]-mean[o])*scale+beta
// ---------------------------------------------------------------------------
__device__ __forceinline__ void bn_precompute(const float* __restrict__ cb,
                                              const float* __restrict__ gamma,
                                              const float* __restrict__ beta,
                                              const float* __restrict__ mean,
                                              const float* __restrict__ var,
                                              float* __restrict__ s_scale,
                                              float* __restrict__ s_bias) {
    for (int o = threadIdx.x; o < COUT; o += 64) {
        float sc = gamma[o] / sqrtf(var[o] + BN_EPS);
        s_scale[o] = sc;
        s_bias[o] = (cb[o] - mean[o]) * sc + beta[o];
    }
}

// ---------------------------------------------------------------------------
// Main BEV kernel: 1 wave per block, lane = BEV pixel, block handles 40 of
// the 80 channels (blockIdx.z). All 4 z offsets computed up front; invalid
// samples clamp to offset 0 (same-address broadcast, ~free) and are killed
// by a mask-FMA — so all 40 float4 gathers are unconditional/independent
// and can be in flight together (branch-free deep MLP). Epilogue: 1 FMA +
// max per channel from LDS-precomputed BN, coalesced 256B/instr stores.
// grid (625, 2, 2), block 64.
// ---------------------------------------------------------------------------
__global__ __launch_bounds__(64, 2) void k_bev(const float* __restrict__ featW,
                                               const float* __restrict__ l2i,
                                               const float* __restrict__ iam,
                                               const float* __restrict__ lam,
                                               const float* __restrict__ cb,
                                               const float* __restrict__ gamma,
                                               const float* __restrict__ beta,
                                               const float* __restrict__ mean,
                                               const float* __restrict__ var,
                                               float* __restrict__ out) {
    __shared__ float smats[NCAM * 16];
    __shared__ float s_scale[COUT];
    __shared__ float s_bias[COUT];
    const int b = blockIdx.y;
    const int cs = blockIdx.z;          // channel half: 0 or 1
    if (threadIdx.x < NCAM)
        compute_cam_mat(b, threadIdx.x, l2i, iam, lam, smats + threadIdx.x * 16);
    bn_precompute(cb, gamma, beta, mean, var, s_scale, s_bias);
    __syncthreads();

    const int P = blockIdx.x * 64 + threadIdx.x;
    const int ix = P / NYV, iy = P % NYV;
    const float x = ix * 0.5f - 50.0f;
    const float y = iy * 0.5f - 50.0f;

    // All 4 z-level offsets + masks up front (no control flow after this).
    const float* base = featW + (size_t)b * NCAM * HWF * COUT + cs * CHALF;
    const float4* src[NZV];
    float vmask[NZV];
    #pragma unroll
    for (int iz = 0; iz < NZV; ++iz) {
        float z = iz * 1.5f - 4.7f;
        int off = project_point(smats, x, y, z);
        vmask[iz] = (off >= 0) ? 1.0f : 0.0f;
        src[iz] = reinterpret_cast<const float4*>(
            base + (size_t)((off >= 0) ? off : 0) * COUT);
    }

    // Issue all 40 independent gathers (4 z x 10 float4 = 160B/lane/z).
    float4 buf[NZV][10];
    #pragma unroll
    for (int iz = 0; iz < NZV; ++iz)
        #pragma unroll
        for (int i = 0; i < 10; i++) buf[iz][i] = src[iz][i];

    float4 acc[10];
    #pragma unroll
    for (int i = 0; i < 10; i++) acc[i] = make_float4(0.f, 0.f, 0.f, 0.f);
    #pragma unroll
    for (int iz = 0; iz < NZV; ++iz) {
        float m = vmask[iz];
        #pragma unroll
        for (int i = 0; i < 10; i++) {
            acc[i].x = fmaf(m, buf[iz][i].x, acc[i].x);
            acc[i].y = fmaf(m, buf[iz][i].y, acc[i].y);
            acc[i].z = fmaf(m, buf[iz][i].z, acc[i].z);
            acc[i].w = fmaf(m, buf[iz][i].w, acc[i].w);
        }
    }

    float* op = out + ((size_t)b * COUT + cs * CHALF) * NPIX + P;
    #pragma unroll
    for (int i = 0; i < 10; i++) {
        float a[4] = {acc[i].x, acc[i].y, acc[i].z, acc[i].w};
        #pragma unroll
        for (int j = 0; j < 4; j++) {
            int o = cs * CHALF + i * 4 + j;
            float val = fmaf(a[j], s_scale[o], s_bias[o]);
            op[(size_t)(i * 4 + j) * NPIX] = fmaxf(val, 0.f);
        }
    }
}

// ---------------------------------------------------------------------------
// Fallback (only if ws too small): fully fused, gathers 256ch from original
// layout and does the 80x256 GEMV per pixel. Slow but correct.
// ---------------------------------------------------------------------------
__global__ __launch_bounds__(64) void k_bev_fb(const float* __restrict__ feat,
                                               const float* __restrict__ l2i,
                                               const float* __restrict__ iam,
                                               const float* __restrict__ lam,
                                               const float* __restrict__ W,
                                               const float* __restrict__ cb,
                                               const float* __restrict__ gamma,
                                               const float* __restrict__ beta,
                                               const float* __restrict__ mean,
                                               const float* __restrict__ var,
                                               float* __restrict__ out) {
    __shared__ float smats[NCAM * 16];
    __shared__ float s_scale[COUT];
    __shared__ float s_bias[COUT];
    const int b = blockIdx.y;
    if (threadIdx.x < NCAM)
        compute_cam_mat(b, threadIdx.x, l2i, iam, lam, smats + threadIdx.x * 16);
    bn_precompute(cb, gamma, beta, mean, var, s_scale, s_bias);
    __syncthreads();

    const int P = blockIdx.x * 64 + threadIdx.x;
    const int ix = P / NYV, iy = P % NYV;
    const float x = ix * 0.5f - 50.0f;
    const float y = iy * 0.5f - 50.0f;

    float acc[COUT];
    #pragma unroll
    for (int o = 0; o < COUT; o++) acc[o] = 0.f;

    for (int iz = 0; iz < NZV; ++iz) {
        float z = iz * 1.5f - 4.7f;
        int off = project_point(smats, x, y, z);
        if (off >= 0) {
            const float* fp = feat + (size_t)b * NCAM * CIN * HWF +
                              (size_t)(off / HWF) * CIN * HWF + (off % HWF);
            for (int c = 0; c < CIN; c++) {
                float fv = fp[(size_t)c * HWF];
                #pragma unroll 8
                for (int o = 0; o < COUT; o++) acc[o] = fmaf(fv, W[o * CIN + c], acc[o]);
            }
        }
    }

    float* op = out + (size_t)b * COUT * NPIX + P;
    for (int o = 0; o < COUT; o++) {
        float val = fmaf(acc[o], s_scale[o], s_bias[o]);
        op[(size_t)o * NPIX] = fmaxf(val, 0.f);
    }
}

extern "C" void kernel_launch(void* const* d_in, const int* in_sizes, int n_in,
                              void* d_out, int out_size, void* d_ws, size_t ws_size,
                              hipStream_t stream) {
    const float* feat  = (const float*)d_in[0];
    const float* l2i   = (const float*)d_in[1];
    const float* iam   = (const float*)d_in[2];
    const float* lam   = (const float*)d_in[3];
    const float* W     = (const float*)d_in[4];
    const float* cb    = (const float*)d_in[5];
    const float* gamma = (const float*)d_in[6];
    const float* beta  = (const float*)d_in[7];
    const float* mean  = (const float*)d_in[8];
    const float* var   = (const float*)d_in[9];
    float* out = (float*)d_out;

    if (ws_size >= WS_NEED) {
        float* featW = (float*)d_ws;
        k_featw<<<dim3(11, 12, 4), 256, 0, stream>>>(feat, W, featW);
        k_bev<<<dim3(625, 2, CSPLIT), 64, 0, stream>>>(featW, l2i, iam, lam, cb,
                                                       gamma, beta, mean, var, out);
    } else {
        k_bev_fb<<<dim3(625, 2), 64, 0, stream>>>(feat, l2i, iam, lam, W, cb, gamma,
                                                  beta, mean, var, out);
    }
}